// Round 7
// baseline (270.228 us; speedup 1.0000x reference)
//
#include <hip/hip_runtime.h>
#include <stdint.h>

// ---------------------------------------------------------------------------
// GraphRec forward, MI355X.
//  K1 k_mlp   : e_r + 2-layer MLPs -> Uh,Vh (f32) + blocked bf16 copies
//  K2 k_gemmQ : Q = R^T@Uh, contiguous row staging into LDS dbuf (16 slabs)
//  K3 k_gather: Rgb[b]=bf16(R[bu[b]]), Sgb[b]=bf16(S[bu[b]])  (copy-shaped)
//  K4 k_gemmP : P_I = Rgb@Vh, P_S = Sgb@Uh  (A = direct bf16x8 from L3-resident
//               gather buffers; 8 k-slabs; depth-4 reg pipeline; no LDS)
//  S1 k_scoreAM  : pre-softmax scores sA (cat(Vb,Ub)) and sM (cat(Ub,Vb))
//  S2 k_HI_scoreB: [softmax-A in-block] H_I = relu((A.P_I)@W_I+b); sB
//  S3 k_HS_H  : [softmax-B] H_S = relu((B.P_S)@W_Sm+b); H = MLP(cat(H_I,H_S))
//  S4 k_Z_G   : [softmax-M] Z = relu((M.Q[bi])@W_Z+b); G = MLP(cat(H,Z))
// ---------------------------------------------------------------------------

typedef short bf16x8 __attribute__((ext_vector_type(8)));
typedef float f32x4 __attribute__((ext_vector_type(4)));

#define PKZ      8
#define PKLEN    1024        // 8192 / PKZ
#define PKITERS  32          // PKLEN / 32
#define QKZ      16
#define QSLAB    512         // u rows per slab
#define QW       128         // i window per block
#define QSTEPS   16          // QSLAB / 32

__device__ __forceinline__ unsigned f2bf1(float f) {
    unsigned x = __float_as_uint(f);
    return (x + 0x7FFFu + ((x >> 16) & 1u)) >> 16;   // RNE f32->bf16
}

__device__ __forceinline__ float wsum(float v) {
    #pragma unroll
    for (int o = 32; o; o >>= 1) v += __shfl_xor(v, o);
    return v;
}

// block-wide softmax stats over a 4096-vector (256-thread block)
__device__ __forceinline__ void block_softmax_stats(const float* __restrict__ s,
                                                    float& m, float& inv) {
    __shared__ float r1[4];
    __shared__ float r2[4];
    int t = threadIdx.x, lane = t & 63, wv = t >> 6;
    float lm = -3.4e38f;
    #pragma unroll
    for (int i = 0; i < 16; ++i) lm = fmaxf(lm, s[t + 256 * i]);
    #pragma unroll
    for (int o = 32; o; o >>= 1) lm = fmaxf(lm, __shfl_xor(lm, o));
    if (lane == 0) r1[wv] = lm;
    __syncthreads();
    m = fmaxf(fmaxf(r1[0], r1[1]), fmaxf(r1[2], r1[3]));
    float ls = 0.f;
    #pragma unroll
    for (int i = 0; i < 16; ++i) ls += __expf(s[t + 256 * i] - m);
    ls = wsum(ls);
    if (lane == 0) r2[wv] = ls;
    __syncthreads();
    inv = 1.f / (r2[0] + r2[1] + r2[2] + r2[3]);
}

// ---------------------------------------------------------------- K1: MLPs
__global__ __launch_bounds__(256) void k_mlp(
    const float* __restrict__ U, const float* __restrict__ V,
    const float* __restrict__ w_r, const float* __restrict__ b_r,
    const float* __restrict__ Wu0, const float* __restrict__ bu0,
    const float* __restrict__ Wu1, const float* __restrict__ bu1,
    const float* __restrict__ Wv0, const float* __restrict__ bv0,
    const float* __restrict__ Wv1, const float* __restrict__ bv1,
    float* __restrict__ Uh, float* __restrict__ Vh,
    unsigned short* __restrict__ Uhb, unsigned short* __restrict__ Vhb)
{
    int gt = blockIdx.x * 256 + threadIdx.x;
    int wid = gt >> 6;
    int lane = gt & 63;

    float er = b_r[lane];
    #pragma unroll
    for (int s = 0; s < 5; ++s) er += (float)(s + 1) * w_r[s * 64 + lane];

    const int isV = (wid >= 2048);
    const float* X  = isV ? V   : U;
    const float* W0 = isV ? Wv0 : Wu0;
    const float* B0 = isV ? bv0 : bu0;
    const float* W1 = isV ? Wv1 : Wu1;
    const float* B1 = isV ? bv1 : bu1;
    float* Hout          = isV ? Vh  : Uh;
    unsigned short* Hb   = isV ? Vhb : Uhb;
    int r0 = (wid & 2047) * 4;

    float x[4];
    #pragma unroll
    for (int j = 0; j < 4; ++j) x[j] = X[(r0 + j) * 64 + lane];

    float h0c = B0[lane];
    for (int k = 0; k < 64; ++k) h0c += __shfl(er, k) * W0[(64 + k) * 64 + lane];

    float h0[4];
    #pragma unroll
    for (int j = 0; j < 4; ++j) h0[j] = h0c;
    for (int k = 0; k < 64; ++k) {
        float wv = W0[k * 64 + lane];
        #pragma unroll
        for (int j = 0; j < 4; ++j) h0[j] += __shfl(x[j], k) * wv;
    }
    #pragma unroll
    for (int j = 0; j < 4; ++j) h0[j] = fmaxf(h0[j], 0.f);

    float h1[4];
    #pragma unroll
    for (int j = 0; j < 4; ++j) h1[j] = B1[lane];
    for (int k = 0; k < 64; ++k) {
        float wv = W1[k * 64 + lane];
        #pragma unroll
        for (int j = 0; j < 4; ++j) h1[j] += __shfl(h0[j], k) * wv;
    }
    #pragma unroll
    for (int j = 0; j < 4; ++j) {
        h1[j] = fmaxf(h1[j], 0.f);
        Hout[(r0 + j) * 64 + lane] = h1[j];
    }
    // blocked bf16: element (r,d) at (r>>3)*512 + (d>>4)*128 + (d&15)*8 + (r&7)
    unsigned pw[2];
    #pragma unroll
    for (int q = 0; q < 2; ++q) pw[q] = f2bf1(h1[2*q]) | (f2bf1(h1[2*q+1]) << 16);
    unsigned short* dst = Hb + (size_t)(r0 >> 3) * 512 + (lane >> 4) * 128
                        + (lane & 15) * 8 + (r0 & 7);
    *(uint2*)dst = make_uint2(pw[0], pw[1]);
}

// ------------------------------------------------------- K2: Q = R^T @ Uh
// grid = 64 i-windows x 16 u-slabs. Per step stage [32u x 128i] f32 (512 B
// contiguous per row) via global_load_lds; dbuf; 1 barrier pair/step.
__global__ __launch_bounds__(256) void k_gemmQ(
    const float* __restrict__ R,
    const unsigned short* __restrict__ Uhb,
    float* __restrict__ Qp)
{
    __shared__ float Abuf[2][4096];   // 2 x 16 KB
    const int t = threadIdx.x;
    const int w = t >> 6, l = t & 63, lg = l >> 4, lr = l & 15;
    const int iw = blockIdx.x & 63;
    const int kz = blockIdx.x >> 6;
    const int i0 = iw * QW;
    const int u0 = kz * QSLAB;

    f32x4 acc[2][4] = {};

    // stage step s into buffer b: wave w, issue q covers rows {8w+2q, 8w+2q+1}
    #define QSTAGE(s, b)                                                          \
    {                                                                             \
        const float* g0 = R + ((size_t)(u0 + (s) * 32 + 8 * w) + (l >> 5)) * 8192 \
                        + i0 + (l & 31) * 4;                                      \
        _Pragma("unroll")                                                         \
        for (int q = 0; q < 4; ++q) {                                             \
            __builtin_amdgcn_global_load_lds(                                     \
                (const __attribute__((address_space(1))) void*)(g0 + (size_t)(q * 2) * 8192), \
                (__attribute__((address_space(3))) void*)((char*)&Abuf[(b)][0]    \
                    + (8 * w + 2 * q) * 512 + l * 16),                            \
                16, 0, 0);                                                        \
        }                                                                         \
    }

    QSTAGE(0, 0);
    __syncthreads();

    for (int s = 0; s < QSTEPS; ++s) {
        if (s + 1 < QSTEPS) QSTAGE(s + 1, (s + 1) & 1);
        const float* Lb = Abuf[s & 1];
        const unsigned short* bb = Uhb + (size_t)(((u0 + s * 32) >> 3) + lg) * 512 + lr * 8;
        bf16x8 bfrag[4];
        #pragma unroll
        for (int c = 0; c < 4; ++c) bfrag[c] = *(const bf16x8*)(bb + c * 128);
        #pragma unroll
        for (int ii = 0; ii < 2; ++ii) {
            float av[8];
            #pragma unroll
            for (int j = 0; j < 8; ++j)
                av[j] = Lb[(8 * lg + j) * 128 + w * 32 + ii * 16 + lr];
            union { bf16x8 v; unsigned u[4]; } af;
            #pragma unroll
            for (int qq = 0; qq < 4; ++qq)
                af.u[qq] = f2bf1(av[2 * qq]) | (f2bf1(av[2 * qq + 1]) << 16);
            #pragma unroll
            for (int c = 0; c < 4; ++c)
                acc[ii][c] = __builtin_amdgcn_mfma_f32_16x16x32_bf16(af.v, bfrag[c], acc[ii][c], 0, 0, 0);
        }
        __syncthreads();
    }

    #pragma unroll
    for (int ii = 0; ii < 2; ++ii) {
        float* out = Qp + (size_t)(kz * 8192 + i0 + w * 32 + ii * 16 + lg * 4) * 64 + lr;
        #pragma unroll
        for (int c = 0; c < 4; ++c) {
            #pragma unroll
            for (int j = 0; j < 4; ++j) out[j * 64 + c * 16] = acc[ii][c][j];
        }
    }
    #undef QSTAGE
}

// ------------------------------------- K3: gather + bf16-pack R[bu], S[bu]
// grid 8192: block r<4096 -> Rgb[r]=bf16(R[bu[r]]); else Sgb[r-4096]=bf16(S[bu[..]])
__global__ __launch_bounds__(256) void k_gather(
    const float* __restrict__ R, const float* __restrict__ S,
    const int* __restrict__ bu,
    unsigned short* __restrict__ Rgb, unsigned short* __restrict__ Sgb)
{
    const int r = blockIdx.x & 4095;
    const int isS = blockIdx.x >> 12;
    const float* src = (isS ? S : R) + (size_t)bu[r] * 8192;
    unsigned short* dst = (isS ? Sgb : Rgb) + (size_t)r * 8192;
    const int t = threadIdx.x;
    #pragma unroll
    for (int it = 0; it < 8; ++it) {
        int idx = it * 1024 + t * 4;
        f32x4 v = *(const f32x4*)(src + idx);
        uint2 pw;
        pw.x = f2bf1(v.x) | (f2bf1(v.y) << 16);
        pw.y = f2bf1(v.z) | (f2bf1(v.w) << 16);
        *(uint2*)(dst + idx) = pw;
    }
}

// ------------------------------------------- K4: P_I and P_S from gathered bf16
// blocks [0, gP): P_I  A = Rgb;  [gP, 2gP): P_S  A = Sgb.  A-frag = one 16 B load.
__global__ __launch_bounds__(256) void k_gemmP(
    const unsigned short* __restrict__ Rgb, const unsigned short* __restrict__ Sgb,
    const unsigned short* __restrict__ Uhb, const unsigned short* __restrict__ Vhb,
    float* __restrict__ PpI, float* __restrict__ PpS)
{
    const int gP = PKZ * 64;
    const int bid = blockIdx.x;
    const int isS = bid >= gP;
    int q = isS ? bid - gP : bid;
    int tile = q & 63, kz = q >> 6;
    const int t = threadIdx.x;
    const int w = t >> 6, l = t & 63, lg = l >> 4, lr = l & 15;

    int brow = tile * 64 + w * 16 + lr;
    const unsigned short* A = (isS ? Sgb : Rgb) + (size_t)brow * 8192 + kz * PKLEN + lg * 8;
    const unsigned short* Bb = (isS ? Uhb : Vhb)
                             + (size_t)((kz * PKLEN) >> 3) * 512 + lr * 8;

    f32x4 acc[4] = {};
    bf16x8 a[4];
    #pragma unroll
    for (int d = 0; d < 4; ++d) a[d] = *(const bf16x8*)(A + d * 32);

    #pragma unroll 4
    for (int ks = 0; ks < PKITERS - 4; ++ks) {
        const int slot = ks & 3;
        bf16x8 av = a[slot];
        a[slot] = *(const bf16x8*)(A + (ks + 4) * 32);
        const unsigned short* bp = Bb + (size_t)(ks * 4 + lg) * 512;
        #pragma unroll
        for (int c = 0; c < 4; ++c) {
            bf16x8 bf = *(const bf16x8*)(bp + c * 128);
            acc[c] = __builtin_amdgcn_mfma_f32_16x16x32_bf16(av, bf, acc[c], 0, 0, 0);
        }
    }
    #pragma unroll
    for (int ks = PKITERS - 4; ks < PKITERS; ++ks) {
        const int slot = ks & 3;
        const unsigned short* bp = Bb + (size_t)(ks * 4 + lg) * 512;
        #pragma unroll
        for (int c = 0; c < 4; ++c) {
            bf16x8 bf = *(const bf16x8*)(bp + c * 128);
            acc[c] = __builtin_amdgcn_mfma_f32_16x16x32_bf16(a[slot], bf, acc[c], 0, 0, 0);
        }
    }

    float* out = (isS ? PpS : PpI)
               + (size_t)(kz * 4096 + tile * 64 + w * 16 + lg * 4) * 64 + lr;
    #pragma unroll
    for (int c = 0; c < 4; ++c) {
        #pragma unroll
        for (int j = 0; j < 4; ++j) out[j * 64 + c * 16] = acc[c][j];
    }
}

// ------------------------------------------------------- S1: scores A and M
__global__ __launch_bounds__(256) void k_scoreAM(
    const int* __restrict__ bu, const int* __restrict__ bi,
    const float* __restrict__ Uh, const float* __restrict__ Vh,
    const float* __restrict__ W1A, const float* __restrict__ b1A,
    const float* __restrict__ w2A, const float* __restrict__ b2A,
    const float* __restrict__ W1M, const float* __restrict__ b1M,
    const float* __restrict__ w2M, const float* __restrict__ b2M,
    float* __restrict__ sA, float* __restrict__ sM)
{
    int gt = blockIdx.x * 256 + threadIdx.x;
    int wid = gt >> 6, lane = gt & 63;
    int b0 = wid * 2;
    float ub[2], vb[2];
    #pragma unroll
    for (int j = 0; j < 2; ++j) {
        ub[j] = Uh[(size_t)bu[b0 + j] * 64 + lane];
        vb[j] = Vh[(size_t)bi[b0 + j] * 64 + lane];
    }
    float hA[2], hM[2];
    #pragma unroll
    for (int j = 0; j < 2; ++j) { hA[j] = b1A[lane]; hM[j] = b1M[lane]; }
    for (int k = 0; k < 64; ++k) {
        float wa0 = W1A[k * 64 + lane], wa1 = W1A[(64 + k) * 64 + lane];
        float wm0 = W1M[k * 64 + lane], wm1 = W1M[(64 + k) * 64 + lane];
        #pragma unroll
        for (int j = 0; j < 2; ++j) {
            float sv = __shfl(vb[j], k), su = __shfl(ub[j], k);
            hA[j] += sv * wa0 + su * wa1;   // cat(Vb, Ub)
            hM[j] += su * wm0 + sv * wm1;   // cat(Ub, Vb)
        }
    }
    float w2a = w2A[lane], w2m = w2M[lane];
    #pragma unroll
    for (int j = 0; j < 2; ++j) {
        float sa = wsum(fmaxf(hA[j], 0.f) * w2a);
        float sm = wsum(fmaxf(hM[j], 0.f) * w2m);
        if (lane == 0) { sA[b0 + j] = sa + b2A[0]; sM[b0 + j] = sm + b2M[0]; }
    }
}

// ------------------------------------------------- S2: H_I and B-scores
__global__ __launch_bounds__(256) void k_HI_scoreB(
    const float* __restrict__ PpI, const float* __restrict__ sA,
    const int* __restrict__ bu, const float* __restrict__ Uh,
    const float* __restrict__ W_I, const float* __restrict__ b_I,
    const float* __restrict__ W1B, const float* __restrict__ b1B,
    const float* __restrict__ w2B, const float* __restrict__ b2B,
    float* __restrict__ HI, float* __restrict__ sB)
{
    float m, inv;
    block_softmax_stats(sA, m, inv);
    int wid = blockIdx.x * 4 + (threadIdx.x >> 6);
    int lane = threadIdx.x & 63;
    int b0 = wid * 2;
    float p[2];
    #pragma unroll
    for (int j = 0; j < 2; ++j) {
        int b = b0 + j;
        float a = 0.f;
        #pragma unroll
        for (int kz = 0; kz < PKZ; ++kz)
            a += PpI[(size_t)(kz * 4096 + b) * 64 + lane];
        p[j] = a * (__expf(sA[b] - m) * inv);
    }
    float h[2];
    #pragma unroll
    for (int j = 0; j < 2; ++j) h[j] = b_I[lane];
    for (int k = 0; k < 64; ++k) {
        float wv = W_I[k * 64 + lane];
        #pragma unroll
        for (int j = 0; j < 2; ++j) h[j] += __shfl(p[j], k) * wv;
    }
    float ub[2];
    #pragma unroll
    for (int j = 0; j < 2; ++j) {
        h[j] = fmaxf(h[j], 0.f);
        HI[(size_t)(b0 + j) * 64 + lane] = h[j];
        ub[j] = Uh[(size_t)bu[b0 + j] * 64 + lane];
    }
    float h2[2];
    #pragma unroll
    for (int j = 0; j < 2; ++j) h2[j] = b1B[lane];
    for (int k = 0; k < 64; ++k) {
        float w0 = W1B[k * 64 + lane], w1 = W1B[(64 + k) * 64 + lane];
        #pragma unroll
        for (int j = 0; j < 2; ++j) h2[j] += __shfl(h[j], k) * w0 + __shfl(ub[j], k) * w1;
    }
    float w2 = w2B[lane];
    #pragma unroll
    for (int j = 0; j < 2; ++j) {
        float sv = wsum(fmaxf(h2[j], 0.f) * w2);
        if (lane == 0) sB[b0 + j] = sv + b2B[0];
    }
}

// ------------------------------------------------- S3: H_S then H
__global__ __launch_bounds__(256) void k_HS_H(
    const float* __restrict__ PpS, const float* __restrict__ sB,
    const float* __restrict__ HI,
    const float* __restrict__ W_Sm, const float* __restrict__ b_Sm,
    const float* __restrict__ Wc0, const float* __restrict__ bc0,
    const float* __restrict__ Wc1, const float* __restrict__ bc1,
    float* __restrict__ Hout)
{
    float m, inv;
    block_softmax_stats(sB, m, inv);
    int wid = blockIdx.x * 4 + (threadIdx.x >> 6);
    int lane = threadIdx.x & 63;
    int b0 = wid * 2;
    float p[2];
    #pragma unroll
    for (int j = 0; j < 2; ++j) {
        int b = b0 + j;
        float a = 0.f;
        #pragma unroll
        for (int kz = 0; kz < PKZ; ++kz)
            a += PpS[(size_t)(kz * 4096 + b) * 64 + lane];
        p[j] = a * (__expf(sB[b] - m) * inv);
    }
    float hs[2];
    #pragma unroll
    for (int j = 0; j < 2; ++j) hs[j] = b_Sm[lane];
    for (int k = 0; k < 64; ++k) {
        float wv = W_Sm[k * 64 + lane];
        #pragma unroll
        for (int j = 0; j < 2; ++j) hs[j] += __shfl(p[j], k) * wv;
    }
    float hi[2];
    #pragma unroll
    for (int j = 0; j < 2; ++j) {
        hs[j] = fmaxf(hs[j], 0.f);
        hi[j] = HI[(size_t)(b0 + j) * 64 + lane];
    }
    float h0[2];
    #pragma unroll
    for (int j = 0; j < 2; ++j) h0[j] = bc0[lane];
    for (int k = 0; k < 64; ++k) {
        float w0 = Wc0[k * 64 + lane], w1 = Wc0[(64 + k) * 64 + lane];
        #pragma unroll
        for (int j = 0; j < 2; ++j) h0[j] += __shfl(hi[j], k) * w0 + __shfl(hs[j], k) * w1;
    }
    #pragma unroll
    for (int j = 0; j < 2; ++j) h0[j] = fmaxf(h0[j], 0.f);
    float h1[2];
    #pragma unroll
    for (int j = 0; j < 2; ++j) h1[j] = bc1[lane];
    for (int k = 0; k < 64; ++k) {
        float wv = Wc1[k * 64 + lane];
        #pragma unroll
        for (int j = 0; j < 2; ++j) h1[j] += __shfl(h0[j], k) * wv;
    }
    #pragma unroll
    for (int j = 0; j < 2; ++j) Hout[(size_t)(b0 + j) * 64 + lane] = fmaxf(h1[j], 0.f);
}

// ------------------------------------------------- S4: Z then G (output)
__global__ __launch_bounds__(256) void k_Z_G(
    const float* __restrict__ Qp, const float* __restrict__ sM,
    const int* __restrict__ bi, const float* __restrict__ H,
    const float* __restrict__ W_Z, const float* __restrict__ b_Z,
    const float* __restrict__ Wg0, const float* __restrict__ bg0,
    const float* __restrict__ Wg1, const float* __restrict__ bg1,
    float* __restrict__ G)
{
    float m, inv;
    block_softmax_stats(sM, m, inv);
    int wid = blockIdx.x * 4 + (threadIdx.x >> 6);
    int lane = threadIdx.x & 63;
    int b0 = wid * 2;
    float p[2];
    #pragma unroll
    for (int j = 0; j < 2; ++j) {
        int b = b0 + j;
        int it = bi[b];
        float a = 0.f;
        #pragma unroll
        for (int kz = 0; kz < QKZ; ++kz)
            a += Qp[(size_t)(kz * 8192 + it) * 64 + lane];
        p[j] = a * (__expf(sM[b] - m) * inv);
    }
    float z[2];
    #pragma unroll
    for (int j = 0; j < 2; ++j) z[j] = b_Z[lane];
    for (int k = 0; k < 64; ++k) {
        float wv = W_Z[k * 64 + lane];
        #pragma unroll
        for (int j = 0; j < 2; ++j) z[j] += __shfl(p[j], k) * wv;
    }
    float hr[2];
    #pragma unroll
    for (int j = 0; j < 2; ++j) {
        z[j] = fmaxf(z[j], 0.f);
        hr[j] = H[(size_t)(b0 + j) * 64 + lane];
    }
    float g0[2];
    #pragma unroll
    for (int j = 0; j < 2; ++j) g0[j] = bg0[lane];
    for (int k = 0; k < 64; ++k) {
        float w0 = Wg0[k * 64 + lane], w1 = Wg0[(64 + k) * 64 + lane];
        #pragma unroll
        for (int j = 0; j < 2; ++j) g0[j] += __shfl(hr[j], k) * w0 + __shfl(z[j], k) * w1;
    }
    #pragma unroll
    for (int j = 0; j < 2; ++j) g0[j] = fmaxf(g0[j], 0.f);
    float g1[2];
    #pragma unroll
    for (int j = 0; j < 2; ++j) g1[j] = bg1[lane];
    for (int k = 0; k < 64; ++k) {
        float wv = Wg1[k * 64 + lane];
        #pragma unroll
        for (int j = 0; j < 2; ++j) g1[j] += __shfl(g0[j], k) * wv;
    }
    #pragma unroll
    for (int j = 0; j < 2; ++j) G[(size_t)(b0 + j) * 64 + lane] = fmaxf(g1[j], 0.f);
}

// ---------------------------------------------------------------------------
extern "C" void kernel_launch(void* const* d_in, const int* in_sizes, int n_in,
                              void* d_out, int out_size, void* d_ws, size_t ws_size,
                              hipStream_t stream)
{
    (void)in_sizes; (void)n_in; (void)out_size; (void)ws_size;
    const int*   bu  = (const int*)  d_in[0];
    const int*   bi  = (const int*)  d_in[1];
    const float* R   = (const float*)d_in[2];
    const float* S   = (const float*)d_in[3];
    const float* U   = (const float*)d_in[4];
    const float* V   = (const float*)d_in[5];
    const float* w_r = (const float*)d_in[6];
    const float* b_r = (const float*)d_in[7];
    const float* Wu0 = (const float*)d_in[8];
    const float* bu0 = (const float*)d_in[9];
    const float* Wu1 = (const float*)d_in[10];
    const float* bu1 = (const float*)d_in[11];
    const float* Wv0 = (const float*)d_in[12];
    const float* bv0 = (const float*)d_in[13];
    const float* Wv1 = (const float*)d_in[14];
    const float* bv1 = (const float*)d_in[15];
    const float* Wc0 = (const float*)d_in[16];
    const float* bc0 = (const float*)d_in[17];
    const float* Wc1 = (const float*)d_in[18];
    const float* bc1 = (const float*)d_in[19];
    const float* Wg0 = (const float*)d_in[20];
    const float* bg0 = (const float*)d_in[21];
    const float* Wg1 = (const float*)d_in[22];
    const float* bg1 = (const float*)d_in[23];
    const float* W_I = (const float*)d_in[24];
    const float* b_I = (const float*)d_in[25];
    const float* W_Sm= (const float*)d_in[26];
    const float* b_Sm= (const float*)d_in[27];
    const float* W1A = (const float*)d_in[28];
    const float* b1A = (const float*)d_in[29];
    const float* w2A = (const float*)d_in[30];
    const float* b2A = (const float*)d_in[31];
    const float* W1B = (const float*)d_in[32];
    const float* b1B = (const float*)d_in[33];
    const float* w2B = (const float*)d_in[34];
    const float* b2B = (const float*)d_in[35];
    const float* W1M = (const float*)d_in[36];
    const float* b1M = (const float*)d_in[37];
    const float* w2M = (const float*)d_in[38];
    const float* b2M = (const float*)d_in[39];
    const float* W_Z = (const float*)d_in[40];
    const float* b_Z = (const float*)d_in[41];

    char* ws = (char*)d_ws;
    size_t off = 0;
    float*          Uh  = (float*)(ws + off);          off += 2ull << 20;
    float*          Vh  = (float*)(ws + off);          off += 2ull << 20;
    unsigned short* Uhb = (unsigned short*)(ws + off); off += 1ull << 20;
    unsigned short* Vhb = (unsigned short*)(ws + off); off += 1ull << 20;
    unsigned short* Rgb = (unsigned short*)(ws + off); off += 64ull << 20;
    unsigned short* Sgb = (unsigned short*)(ws + off); off += 64ull << 20;
    float*          PpI = (float*)(ws + off);          off += (size_t)PKZ << 20;
    float*          PpS = (float*)(ws + off);          off += (size_t)PKZ << 20;
    float*          Qp  = (float*)(ws + off);          off += (size_t)(2 * QKZ) << 20;
    float*          sA  = (float*)(ws + off);
    float*          sM  = sA + 4096;
    float*          sB  = sA + 8192;                   off += 3 * 4096 * 4 + 4096;
    float*          HI  = (float*)(ws + off);          off += 1ull << 20;
    float*          Hh  = (float*)(ws + off);

    k_mlp<<<1024, 256, 0, stream>>>(U, V, w_r, b_r, Wu0, bu0, Wu1, bu1,
                                    Wv0, bv0, Wv1, bv1, Uh, Vh, Uhb, Vhb);
    k_gemmQ<<<64 * QKZ, 256, 0, stream>>>(R, Uhb, Qp);
    k_gather<<<8192, 256, 0, stream>>>(R, S, bu, Rgb, Sgb);
    k_gemmP<<<2 * PKZ * 64, 256, 0, stream>>>(Rgb, Sgb, Uhb, Vhb, PpI, PpS);
    k_scoreAM<<<512, 256, 0, stream>>>(bu, bi, Uh, Vh, W1A, b1A, w2A, b2A,
                                       W1M, b1M, w2M, b2M, sA, sM);
    k_HI_scoreB<<<512, 256, 0, stream>>>(PpI, sA, bu, Uh, W_I, b_I,
                                         W1B, b1B, w2B, b2B, HI, sB);
    k_HS_H<<<512, 256, 0, stream>>>(PpS, sB, HI, W_Sm, b_Sm, Wc0, bc0, Wc1, bc1,
                                    Hh);
    k_Z_G<<<512, 256, 0, stream>>>(Qp, sM, bi, Hh, W_Z, b_Z, Wg0, bg0, Wg1, bg1,
                                   (float*)d_out);
}

// Round 8
// 221.712 us; speedup vs baseline: 1.2188x; 1.2188x over previous
//
#include <hip/hip_runtime.h>
#include <stdint.h>

// ---------------------------------------------------------------------------
// GraphRec forward, MI355X.
//  K1 k_mlp   : e_r + 2-layer MLPs -> Uh,Vh (f32) + blocked bf16 copies
//  K2 k_gemmQ : Q = R^T@Uh. Counted-vmcnt pipeline (T3/T4): 4-deep LDS
//               buffers, raw s_barrier + s_waitcnt vmcnt(12) -- never drains
//               to 0 in the main loop. 64 i-windows x 8 u-slabs.
//  K3 k_gemmP : P_I = R[bu]@Vh, P_S = S[bu]@Uh (32 k-slabs, reg pipeline,
//               B slab in LDS)  [round-5 P, measured ~50-55us]
//  S1 k_scoreAM  : pre-softmax scores sA (cat(Vb,Ub)) and sM (cat(Ub,Vb))
//  S2 k_HI_scoreB: [softmax-A in-block] H_I = relu((A.P_I)@W_I+b); sB
//  S3 k_HS_H  : [softmax-B] H_S = relu((B.P_S)@W_Sm+b); H = MLP(cat(H_I,H_S))
//  S4 k_Z_G   : [softmax-M] Z = relu((M.Q[bi])@W_Z+b); G = MLP(cat(H,Z))
// ---------------------------------------------------------------------------

typedef short bf16x8 __attribute__((ext_vector_type(8)));
typedef float f32x4 __attribute__((ext_vector_type(4)));

#define PKZ      32
#define PKLEN    256         // 8192 / PKZ
#define PKITERS  8           // PKLEN / 32
#define QKZ      8
#define QSLAB    1024        // u rows per slab
#define QW       128         // i window per block
#define QSTEPS   32          // QSLAB / 32

__device__ __forceinline__ unsigned f2bf1(float f) {
    unsigned x = __float_as_uint(f);
    return (x + 0x7FFFu + ((x >> 16) & 1u)) >> 16;   // RNE f32->bf16
}

__device__ __forceinline__ float wsum(float v) {
    #pragma unroll
    for (int o = 32; o; o >>= 1) v += __shfl_xor(v, o);
    return v;
}

// block-wide softmax stats over a 4096-vector (256-thread block)
__device__ __forceinline__ void block_softmax_stats(const float* __restrict__ s,
                                                    float& m, float& inv) {
    __shared__ float r1[4];
    __shared__ float r2[4];
    int t = threadIdx.x, lane = t & 63, wv = t >> 6;
    float lm = -3.4e38f;
    #pragma unroll
    for (int i = 0; i < 16; ++i) lm = fmaxf(lm, s[t + 256 * i]);
    #pragma unroll
    for (int o = 32; o; o >>= 1) lm = fmaxf(lm, __shfl_xor(lm, o));
    if (lane == 0) r1[wv] = lm;
    __syncthreads();
    m = fmaxf(fmaxf(r1[0], r1[1]), fmaxf(r1[2], r1[3]));
    float ls = 0.f;
    #pragma unroll
    for (int i = 0; i < 16; ++i) ls += __expf(s[t + 256 * i] - m);
    ls = wsum(ls);
    if (lane == 0) r2[wv] = ls;
    __syncthreads();
    inv = 1.f / (r2[0] + r2[1] + r2[2] + r2[3]);
}

// ---------------------------------------------------------------- K1: MLPs
__global__ __launch_bounds__(256) void k_mlp(
    const float* __restrict__ U, const float* __restrict__ V,
    const float* __restrict__ w_r, const float* __restrict__ b_r,
    const float* __restrict__ Wu0, const float* __restrict__ bu0,
    const float* __restrict__ Wu1, const float* __restrict__ bu1,
    const float* __restrict__ Wv0, const float* __restrict__ bv0,
    const float* __restrict__ Wv1, const float* __restrict__ bv1,
    float* __restrict__ Uh, float* __restrict__ Vh,
    unsigned short* __restrict__ Uhb, unsigned short* __restrict__ Vhb)
{
    int gt = blockIdx.x * 256 + threadIdx.x;
    int wid = gt >> 6;
    int lane = gt & 63;

    float er = b_r[lane];
    #pragma unroll
    for (int s = 0; s < 5; ++s) er += (float)(s + 1) * w_r[s * 64 + lane];

    const int isV = (wid >= 2048);
    const float* X  = isV ? V   : U;
    const float* W0 = isV ? Wv0 : Wu0;
    const float* B0 = isV ? bv0 : bu0;
    const float* W1 = isV ? Wv1 : Wu1;
    const float* B1 = isV ? bv1 : bu1;
    float* Hout          = isV ? Vh  : Uh;
    unsigned short* Hb   = isV ? Vhb : Uhb;
    int r0 = (wid & 2047) * 4;

    float x[4];
    #pragma unroll
    for (int j = 0; j < 4; ++j) x[j] = X[(r0 + j) * 64 + lane];

    float h0c = B0[lane];
    for (int k = 0; k < 64; ++k) h0c += __shfl(er, k) * W0[(64 + k) * 64 + lane];

    float h0[4];
    #pragma unroll
    for (int j = 0; j < 4; ++j) h0[j] = h0c;
    for (int k = 0; k < 64; ++k) {
        float wv = W0[k * 64 + lane];
        #pragma unroll
        for (int j = 0; j < 4; ++j) h0[j] += __shfl(x[j], k) * wv;
    }
    #pragma unroll
    for (int j = 0; j < 4; ++j) h0[j] = fmaxf(h0[j], 0.f);

    float h1[4];
    #pragma unroll
    for (int j = 0; j < 4; ++j) h1[j] = B1[lane];
    for (int k = 0; k < 64; ++k) {
        float wv = W1[k * 64 + lane];
        #pragma unroll
        for (int j = 0; j < 4; ++j) h1[j] += __shfl(h0[j], k) * wv;
    }
    #pragma unroll
    for (int j = 0; j < 4; ++j) {
        h1[j] = fmaxf(h1[j], 0.f);
        Hout[(r0 + j) * 64 + lane] = h1[j];
    }
    // blocked bf16: element (r,d) at (r>>3)*512 + (d>>4)*128 + (d&15)*8 + (r&7)
    unsigned pw[2];
    #pragma unroll
    for (int q = 0; q < 2; ++q) pw[q] = f2bf1(h1[2*q]) | (f2bf1(h1[2*q+1]) << 16);
    unsigned short* dst = Hb + (size_t)(r0 >> 3) * 512 + (lane >> 4) * 128
                        + (lane & 15) * 8 + (r0 & 7);
    *(uint2*)dst = make_uint2(pw[0], pw[1]);
}

// ------------------------------------------------------- K2: Q = R^T @ Uh
// Counted-vmcnt pipeline: 4 LDS buffers [32u x 128i] f32 (16 KB each).
// Per step & wave: 4 global_load_lds (2 rows each, 512 B contiguous per row).
// Loop: vmcnt(12) [oldest stage landed] -> barrier -> ds_read+MFMA ->
//       lgkmcnt(0)+sched_barrier -> barrier -> issue stage s+4.
__global__ __launch_bounds__(256) void k_gemmQ(
    const float* __restrict__ R,
    const unsigned short* __restrict__ Uhb,
    float* __restrict__ Qp)
{
    __shared__ float Abuf[4][32 * QW];   // 4 x 16 KB
    const int t = threadIdx.x;
    const int w = t >> 6, l = t & 63, lg = l >> 4, lr = l & 15;
    const int iw = blockIdx.x & 63;
    const int kz = blockIdx.x >> 6;
    const int i0 = iw * QW;
    const int u0 = kz * QSLAB;

    f32x4 acc[2][4] = {};

    // stage step s into Abuf[s&3]; wave w inst q covers tile rows 2*(4q+w)..+1
    #define QSTAGE(s)                                                             \
    {                                                                             \
        const int bufn = (s) & 3;                                                 \
        _Pragma("unroll")                                                         \
        for (int q = 0; q < 4; ++q) {                                             \
            const int rloc = 2 * (4 * q + w);                                     \
            const float* g = R + ((size_t)(u0 + (s) * 32 + rloc) + (l >> 5)) * 8192 \
                           + i0 + (l & 31) * 4;                                   \
            __builtin_amdgcn_global_load_lds(                                     \
                (const __attribute__((address_space(1))) void*)g,                 \
                (__attribute__((address_space(3))) void*)((char*)&Abuf[bufn][0]   \
                    + rloc * 512 + l * 16),                                       \
                16, 0, 0);                                                        \
        }                                                                         \
    }

    QSTAGE(0); QSTAGE(1); QSTAGE(2); QSTAGE(3);   // 16 insts/wave in flight

    for (int s = 0; s < QSTEPS; ++s) {
        // wait until only 3 newer stages (12 insts) outstanding -> stage s done
        asm volatile("s_waitcnt vmcnt(12)" ::: "memory");
        __builtin_amdgcn_s_barrier();

        const float* Lb = &Abuf[s & 3][0];
        const unsigned short* bb = Uhb
            + (size_t)(((u0 + s * 32) >> 3) + lg) * 512 + lr * 8;
        bf16x8 bfrag[4];
        #pragma unroll
        for (int c = 0; c < 4; ++c) bfrag[c] = *(const bf16x8*)(bb + c * 128);

        #pragma unroll
        for (int f = 0; f < 2; ++f) {
            const int iloc = w * 32 + f * 16 + lr;
            float av[8];
            #pragma unroll
            for (int j = 0; j < 8; ++j) av[j] = Lb[(8 * lg + j) * QW + iloc];
            union { bf16x8 v; unsigned u[4]; } af;
            #pragma unroll
            for (int qq = 0; qq < 4; ++qq)
                af.u[qq] = f2bf1(av[2 * qq]) | (f2bf1(av[2 * qq + 1]) << 16);
            #pragma unroll
            for (int c = 0; c < 4; ++c)
                acc[f][c] = __builtin_amdgcn_mfma_f32_16x16x32_bf16(af.v, bfrag[c], acc[f][c], 0, 0, 0);
        }

        // all my LDS reads retired; then block-wide barrier -> safe to overwrite
        asm volatile("s_waitcnt lgkmcnt(0)" ::: "memory");
        __builtin_amdgcn_sched_barrier(0);
        __builtin_amdgcn_s_barrier();
        if (s + 4 < QSTEPS) QSTAGE(s + 4);
    }

    #pragma unroll
    for (int f = 0; f < 2; ++f) {
        float* out = Qp + (size_t)(kz * 8192 + i0 + w * 32 + f * 16 + lg * 4) * 64 + lr;
        #pragma unroll
        for (int c = 0; c < 4; ++c) {
            #pragma unroll
            for (int j = 0; j < 4; ++j) out[j * 64 + c * 16] = acc[f][c][j];
        }
    }
    #undef QSTAGE
}

// ------------------------------------------- K3: P_I and P_S (row gathers)
__global__ __launch_bounds__(256) void k_gemmP(
    const float* __restrict__ R, const float* __restrict__ S,
    const int* __restrict__ bu,
    const unsigned short* __restrict__ Uhb, const unsigned short* __restrict__ Vhb,
    float* __restrict__ PpI, float* __restrict__ PpS)
{
    __shared__ short Bsl[16384];        // 32 KB: bf16 B slab (blocked layout)
    const int bid = blockIdx.x;
    const int t = threadIdx.x;
    const int w = t >> 6, l = t & 63, lg = l >> 4, lr = l & 15;

    f32x4 acc[4] = {};

    const int gP = PKZ * 64;
    const int isS = bid >= gP;
    int q = isS ? bid - gP : bid;
    int tile = q & 63, kz = q >> 6;

    // stage 32 KB B slab (contiguous in blocked layout): linear copy
    const char* Bg = (const char*)((isS ? Uhb : Vhb) + (size_t)kz * 16384);
    #pragma unroll
    for (int ii = 0; ii < 8; ++ii) {
        __builtin_amdgcn_global_load_lds(
            (const __attribute__((address_space(1))) void*)(Bg + ii * 4096 + t * 16),
            (__attribute__((address_space(3))) void*)((char*)Bsl + ii * 4096 + t * 16),
            16, 0, 0);
    }

    int brow = tile * 64 + w * 16 + lr;
    int ridx = bu[brow];
    const float* A = (isS ? S : R) + (size_t)ridx * 8192 + kz * PKLEN + lg * 8;

    f32x4 b0[4], b1[4];
    #pragma unroll
    for (int d = 0; d < 4; ++d) {
        b0[d] = ((const f32x4*)(A + d * 32))[0];
        b1[d] = ((const f32x4*)(A + d * 32))[1];
    }
    __syncthreads();   // B slab (and prologue A) resident

    #pragma unroll
    for (int ks = 0; ks < PKITERS; ++ks) {
        const int slot = ks & 3;
        union { bf16x8 v; unsigned u[4]; } af;
        af.u[0] = f2bf1(b0[slot].x) | (f2bf1(b0[slot].y) << 16);
        af.u[1] = f2bf1(b0[slot].z) | (f2bf1(b0[slot].w) << 16);
        af.u[2] = f2bf1(b1[slot].x) | (f2bf1(b1[slot].y) << 16);
        af.u[3] = f2bf1(b1[slot].z) | (f2bf1(b1[slot].w) << 16);
        if (ks + 4 < PKITERS) {
            b0[slot] = ((const f32x4*)(A + (ks + 4) * 32))[0];
            b1[slot] = ((const f32x4*)(A + (ks + 4) * 32))[1];
        }
        const short* bp = Bsl + (ks * 4 + lg) * 512 + lr * 8;
        #pragma unroll
        for (int c = 0; c < 4; ++c) {
            bf16x8 bf = *(const bf16x8*)(bp + c * 128);
            acc[c] = __builtin_amdgcn_mfma_f32_16x16x32_bf16(af.v, bf, acc[c], 0, 0, 0);
        }
    }

    float* out = (isS ? PpS : PpI)
               + (size_t)(kz * 4096 + tile * 64 + w * 16 + lg * 4) * 64 + lr;
    #pragma unroll
    for (int c = 0; c < 4; ++c) {
        #pragma unroll
        for (int j = 0; j < 4; ++j) out[j * 64 + c * 16] = acc[c][j];
    }
}

// ------------------------------------------------------- S1: scores A and M
__global__ __launch_bounds__(256) void k_scoreAM(
    const int* __restrict__ bu, const int* __restrict__ bi,
    const float* __restrict__ Uh, const float* __restrict__ Vh,
    const float* __restrict__ W1A, const float* __restrict__ b1A,
    const float* __restrict__ w2A, const float* __restrict__ b2A,
    const float* __restrict__ W1M, const float* __restrict__ b1M,
    const float* __restrict__ w2M, const float* __restrict__ b2M,
    float* __restrict__ sA, float* __restrict__ sM)
{
    int gt = blockIdx.x * 256 + threadIdx.x;
    int wid = gt >> 6, lane = gt & 63;
    int b0 = wid * 2;
    float ub[2], vb[2];
    #pragma unroll
    for (int j = 0; j < 2; ++j) {
        ub[j] = Uh[(size_t)bu[b0 + j] * 64 + lane];
        vb[j] = Vh[(size_t)bi[b0 + j] * 64 + lane];
    }
    float hA[2], hM[2];
    #pragma unroll
    for (int j = 0; j < 2; ++j) { hA[j] = b1A[lane]; hM[j] = b1M[lane]; }
    for (int k = 0; k < 64; ++k) {
        float wa0 = W1A[k * 64 + lane], wa1 = W1A[(64 + k) * 64 + lane];
        float wm0 = W1M[k * 64 + lane], wm1 = W1M[(64 + k) * 64 + lane];
        #pragma unroll
        for (int j = 0; j < 2; ++j) {
            float sv = __shfl(vb[j], k), su = __shfl(ub[j], k);
            hA[j] += sv * wa0 + su * wa1;   // cat(Vb, Ub)
            hM[j] += su * wm0 + sv * wm1;   // cat(Ub, Vb)
        }
    }
    float w2a = w2A[lane], w2m = w2M[lane];
    #pragma unroll
    for (int j = 0; j < 2; ++j) {
        float sa = wsum(fmaxf(hA[j], 0.f) * w2a);
        float sm = wsum(fmaxf(hM[j], 0.f) * w2m);
        if (lane == 0) { sA[b0 + j] = sa + b2A[0]; sM[b0 + j] = sm + b2M[0]; }
    }
}

// ------------------------------------------------- S2: H_I and B-scores
__global__ __launch_bounds__(256) void k_HI_scoreB(
    const float* __restrict__ PpI, const float* __restrict__ sA,
    const int* __restrict__ bu, const float* __restrict__ Uh,
    const float* __restrict__ W_I, const float* __restrict__ b_I,
    const float* __restrict__ W1B, const float* __restrict__ b1B,
    const float* __restrict__ w2B, const float* __restrict__ b2B,
    float* __restrict__ HI, float* __restrict__ sB)
{
    float m, inv;
    block_softmax_stats(sA, m, inv);
    int wid = blockIdx.x * 4 + (threadIdx.x >> 6);
    int lane = threadIdx.x & 63;
    int b0 = wid * 2;
    float p[2];
    #pragma unroll
    for (int j = 0; j < 2; ++j) {
        int b = b0 + j;
        float a = 0.f;
        #pragma unroll 8
        for (int kz = 0; kz < PKZ; ++kz)
            a += PpI[(size_t)(kz * 4096 + b) * 64 + lane];
        p[j] = a * (__expf(sA[b] - m) * inv);
    }
    float h[2];
    #pragma unroll
    for (int j = 0; j < 2; ++j) h[j] = b_I[lane];
    for (int k = 0; k < 64; ++k) {
        float wv = W_I[k * 64 + lane];
        #pragma unroll
        for (int j = 0; j < 2; ++j) h[j] += __shfl(p[j], k) * wv;
    }
    float ub[2];
    #pragma unroll
    for (int j = 0; j < 2; ++j) {
        h[j] = fmaxf(h[j], 0.f);
        HI[(size_t)(b0 + j) * 64 + lane] = h[j];
        ub[j] = Uh[(size_t)bu[b0 + j] * 64 + lane];
    }
    float h2[2];
    #pragma unroll
    for (int j = 0; j < 2; ++j) h2[j] = b1B[lane];
    for (int k = 0; k < 64; ++k) {
        float w0 = W1B[k * 64 + lane], w1 = W1B[(64 + k) * 64 + lane];
        #pragma unroll
        for (int j = 0; j < 2; ++j) h2[j] += __shfl(h[j], k) * w0 + __shfl(ub[j], k) * w1;
    }
    float w2 = w2B[lane];
    #pragma unroll
    for (int j = 0; j < 2; ++j) {
        float sv = wsum(fmaxf(h2[j], 0.f) * w2);
        if (lane == 0) sB[b0 + j] = sv + b2B[0];
    }
}

// ------------------------------------------------- S3: H_S then H
__global__ __launch_bounds__(256) void k_HS_H(
    const float* __restrict__ PpS, const float* __restrict__ sB,
    const float* __restrict__ HI,
    const float* __restrict__ W_Sm, const float* __restrict__ b_Sm,
    const float* __restrict__ Wc0, const float* __restrict__ bc0,
    const float* __restrict__ Wc1, const float* __restrict__ bc1,
    float* __restrict__ Hout)
{
    float m, inv;
    block_softmax_stats(sB, m, inv);
    int wid = blockIdx.x * 4 + (threadIdx.x >> 6);
    int lane = threadIdx.x & 63;
    int b0 = wid * 2;
    float p[2];
    #pragma unroll
    for (int j = 0; j < 2; ++j) {
        int b = b0 + j;
        float a = 0.f;
        #pragma unroll 8
        for (int kz = 0; kz < PKZ; ++kz)
            a += PpS[(size_t)(kz * 4096 + b) * 64 + lane];
        p[j] = a * (__expf(sB[b] - m) * inv);
    }
    float hs[2];
    #pragma unroll
    for (int j = 0; j < 2; ++j) hs[j] = b_Sm[lane];
    for (int k = 0; k < 64; ++k) {
        float wv = W_Sm[k * 64 + lane];
        #pragma unroll
        for (int j = 0; j < 2; ++j) hs[j] += __shfl(p[j], k) * wv;
    }
    float hi[2];
    #pragma unroll
    for (int j = 0; j < 2; ++j) {
        hs[j] = fmaxf(hs[j], 0.f);
        hi[j] = HI[(size_t)(b0 + j) * 64 + lane];
    }
    float h0[2];
    #pragma unroll
    for (int j = 0; j < 2; ++j) h0[j] = bc0[lane];
    for (int k = 0; k < 64; ++k) {
        float w0 = Wc0[k * 64 + lane], w1 = Wc0[(64 + k) * 64 + lane];
        #pragma unroll
        for (int j = 0; j < 2; ++j) h0[j] += __shfl(hi[j], k) * w0 + __shfl(hs[j], k) * w1;
    }
    #pragma unroll
    for (int j = 0; j < 2; ++j) h0[j] = fmaxf(h0[j], 0.f);
    float h1[2];
    #pragma unroll
    for (int j = 0; j < 2; ++j) h1[j] = bc1[lane];
    for (int k = 0; k < 64; ++k) {
        float wv = Wc1[k * 64 + lane];
        #pragma unroll
        for (int j = 0; j < 2; ++j) h1[j] += __shfl(h0[j], k) * wv;
    }
    #pragma unroll
    for (int j = 0; j < 2; ++j) Hout[(size_t)(b0 + j) * 64 + lane] = fmaxf(h1[j], 0.f);
}

// ------------------------------------------------- S4: Z then G (output)
__global__ __launch_bounds__(256) void k_Z_G(
    const float* __restrict__ Qp, const float* __restrict__ sM,
    const int* __restrict__ bi, const float* __restrict__ H,
    const float* __restrict__ W_Z, const float* __restrict__ b_Z,
    const float* __restrict__ Wg0, const float* __restrict__ bg0,
    const float* __restrict__ Wg1, const float* __restrict__ bg1,
    float* __restrict__ G)
{
    float m, inv;
    block_softmax_stats(sM, m, inv);
    int wid = blockIdx.x * 4 + (threadIdx.x >> 6);
    int lane = threadIdx.x & 63;
    int b0 = wid * 2;
    float p[2];
    #pragma unroll
    for (int j = 0; j < 2; ++j) {
        int b = b0 + j;
        int it = bi[b];
        float a = 0.f;
        #pragma unroll
        for (int kz = 0; kz < QKZ; ++kz)
            a += Qp[(size_t)(kz * 8192 + it) * 64 + lane];
        p[j] = a * (__expf(sM[b] - m) * inv);
    }
    float z[2];
    #pragma unroll
    for (int j = 0; j < 2; ++j) z[j] = b_Z[lane];
    for (int k = 0; k < 64; ++k) {
        float wv = W_Z[k * 64 + lane];
        #pragma unroll
        for (int j = 0; j < 2; ++j) z[j] += __shfl(p[j], k) * wv;
    }
    float hr[2];
    #pragma unroll
    for (int j = 0; j < 2; ++j) {
        z[j] = fmaxf(z[j], 0.f);
        hr[j] = H[(size_t)(b0 + j) * 64 + lane];
    }
    float g0[2];
    #pragma unroll
    for (int j = 0; j < 2; ++j) g0[j] = bg0[lane];
    for (int k = 0; k < 64; ++k) {
        float w0 = Wg0[k * 64 + lane], w1 = Wg0[(64 + k) * 64 + lane];
        #pragma unroll
        for (int j = 0; j < 2; ++j) g0[j] += __shfl(hr[j], k) * w0 + __shfl(z[j], k) * w1;
    }
    #pragma unroll
    for (int j = 0; j < 2; ++j) g0[j] = fmaxf(g0[j], 0.f);
    float g1[2];
    #pragma unroll
    for (int j = 0; j < 2; ++j) g1[j] = bg1[lane];
    for (int k = 0; k < 64; ++k) {
        float wv = Wg1[k * 64 + lane];
        #pragma unroll
        for (int j = 0; j < 2; ++j) g1[j] += __shfl(g0[j], k) * wv;
    }
    #pragma unroll
    for (int j = 0; j < 2; ++j) G[(size_t)(b0 + j) * 64 + lane] = fmaxf(g1[j], 0.f);
}

// ---------------------------------------------------------------------------
extern "C" void kernel_launch(void* const* d_in, const int* in_sizes, int n_in,
                              void* d_out, int out_size, void* d_ws, size_t ws_size,
                              hipStream_t stream)
{
    (void)in_sizes; (void)n_in; (void)out_size; (void)ws_size;
    const int*   bu  = (const int*)  d_in[0];
    const int*   bi  = (const int*)  d_in[1];
    const float* R   = (const float*)d_in[2];
    const float* S   = (const float*)d_in[3];
    const float* U   = (const float*)d_in[4];
    const float* V   = (const float*)d_in[5];
    const float* w_r = (const float*)d_in[6];
    const float* b_r = (const float*)d_in[7];
    const float* Wu0 = (const float*)d_in[8];
    const float* bu0 = (const float*)d_in[9];
    const float* Wu1 = (const float*)d_in[10];
    const float* bu1 = (const float*)d_in[11];
    const float* Wv0 = (const float*)d_in[12];
    const float* bv0 = (const float*)d_in[13];
    const float* Wv1 = (const float*)d_in[14];
    const float* bv1 = (const float*)d_in[15];
    const float* Wc0 = (const float*)d_in[16];
    const float* bc0 = (const float*)d_in[17];
    const float* Wc1 = (const float*)d_in[18];
    const float* bc1 = (const float*)d_in[19];
    const float* Wg0 = (const float*)d_in[20];
    const float* bg0 = (const float*)d_in[21];
    const float* Wg1 = (const float*)d_in[22];
    const float* bg1 = (const float*)d_in[23];
    const float* W_I = (const float*)d_in[24];
    const float* b_I = (const float*)d_in[25];
    const float* W_Sm= (const float*)d_in[26];
    const float* b_Sm= (const float*)d_in[27];
    const float* W1A = (const float*)d_in[28];
    const float* b1A = (const float*)d_in[29];
    const float* w2A = (const float*)d_in[30];
    const float* b2A = (const float*)d_in[31];
    const float* W1B = (const float*)d_in[32];
    const float* b1B = (const float*)d_in[33];
    const float* w2B = (const float*)d_in[34];
    const float* b2B = (const float*)d_in[35];
    const float* W1M = (const float*)d_in[36];
    const float* b1M = (const float*)d_in[37];
    const float* w2M = (const float*)d_in[38];
    const float* b2M = (const float*)d_in[39];
    const float* W_Z = (const float*)d_in[40];
    const float* b_Z = (const float*)d_in[41];

    char* ws = (char*)d_ws;
    size_t off = 0;
    float*          Uh  = (float*)(ws + off);          off += 2ull << 20;
    float*          Vh  = (float*)(ws + off);          off += 2ull << 20;
    unsigned short* Uhb = (unsigned short*)(ws + off); off += 1ull << 20;
    unsigned short* Vhb = (unsigned short*)(ws + off); off += 1ull << 20;
    float*          PpI = (float*)(ws + off);          off += (size_t)PKZ << 20;
    float*          PpS = (float*)(ws + off);          off += (size_t)PKZ << 20;
    float*          Qp  = (float*)(ws + off);          off += (size_t)(2 * QKZ) << 20;
    float*          sA  = (float*)(ws + off);
    float*          sM  = sA + 4096;
    float*          sB  = sA + 8192;                   off += 3 * 4096 * 4 + 4096;
    float*          HI  = (float*)(ws + off);          off += 1ull << 20;
    float*          Hh  = (float*)(ws + off);

    k_mlp<<<1024, 256, 0, stream>>>(U, V, w_r, b_r, Wu0, bu0, Wu1, bu1,
                                    Wv0, bv0, Wv1, bv1, Uh, Vh, Uhb, Vhb);
    k_gemmQ<<<64 * QKZ, 256, 0, stream>>>(R, Uhb, Qp);
    k_gemmP<<<2 * PKZ * 64, 256, 0, stream>>>(R, S, bu, Uhb, Vhb, PpI, PpS);
    k_scoreAM<<<512, 256, 0, stream>>>(bu, bi, Uh, Vh, W1A, b1A, w2A, b2A,
                                       W1M, b1M, w2M, b2M, sA, sM);
    k_HI_scoreB<<<512, 256, 0, stream>>>(PpI, sA, bu, Uh, W_I, b_I,
                                         W1B, b1B, w2B, b2B, HI, sB);
    k_HS_H<<<512, 256, 0, stream>>>(PpS, sB, HI, W_Sm, b_Sm, Wc0, bc0, Wc1, bc1,
                                    Hh);
    k_Z_G<<<512, 256, 0, stream>>>(Qp, sM, bi, Hh, W_Z, b_Z, Wg0, bg0, Wg1, bg1,
                                   (float*)d_out);
}

// Round 9
// 201.312 us; speedup vs baseline: 1.3423x; 1.1013x over previous
//
#include <hip/hip_runtime.h>
#include <stdint.h>

// ---------------------------------------------------------------------------
// GraphRec forward, MI355X.
//  K1 k_mlp  : e_r + 2-layer MLPs -> Uh,Vh (f32) + blocked bf16 copies
//  K2 k_gemm : merged, interleaved (bid%3==0 -> Q, else P):
//    Q: R^T@Uh. Counted-vmcnt pipeline, 3-deep 20KB LDS buffers holding BOTH
//       the A tile (16KB) and the B slice (4KB) so in-loop B reads are
//       ds_read (lgkmcnt) and the vmcnt queue stays pure staging.
//       vmcnt(10) steady state; tail steps vmcnt(5)/vmcnt(0).
//    P: P_I = R[bu]@Vh, P_S = S[bu]@Uh. 8 k-slabs, depth-4 f32 reg pipeline,
//       B direct from global blocked bf16 (L2-hot; LDS-staging was neutral).
//  S1 k_scoreAM  : pre-softmax scores sA (cat(Vb,Ub)) and sM (cat(Ub,Vb))
//  S2 k_HI_scoreB: [softmax-A in-block] H_I = relu((A.P_I)@W_I+b); sB
//  S3 k_HS_H : [softmax-B] H_S = relu((B.P_S)@W_Sm+b); H = MLP(cat(H_I,H_S))
//  S4 k_Z_G  : [softmax-M] Z = relu((M.Q[bi])@W_Z+b); G = MLP(cat(H,Z))
// ---------------------------------------------------------------------------

typedef short bf16x8 __attribute__((ext_vector_type(8)));
typedef float f32x4 __attribute__((ext_vector_type(4)));

#define PKZ      8
#define PKLEN    1024        // 8192 / PKZ
#define PKITERS  32          // PKLEN / 32
#define QKZ      8
#define QSLAB    1024        // u rows per slab
#define QW       128         // i window per block
#define QSTEPS   32          // QSLAB / 32
#define QBLOCKS  512         // 64 iw x 8 kz
#define PBLOCKS  1024        // 2 * PKZ * 64

__device__ __forceinline__ unsigned f2bf1(float f) {
    unsigned x = __float_as_uint(f);
    return (x + 0x7FFFu + ((x >> 16) & 1u)) >> 16;   // RNE f32->bf16
}

__device__ __forceinline__ float wsum(float v) {
    #pragma unroll
    for (int o = 32; o; o >>= 1) v += __shfl_xor(v, o);
    return v;
}

// block-wide softmax stats over a 4096-vector (256-thread block)
__device__ __forceinline__ void block_softmax_stats(const float* __restrict__ s,
                                                    float& m, float& inv) {
    __shared__ float r1[4];
    __shared__ float r2[4];
    int t = threadIdx.x, lane = t & 63, wv = t >> 6;
    float lm = -3.4e38f;
    #pragma unroll
    for (int i = 0; i < 16; ++i) lm = fmaxf(lm, s[t + 256 * i]);
    #pragma unroll
    for (int o = 32; o; o >>= 1) lm = fmaxf(lm, __shfl_xor(lm, o));
    if (lane == 0) r1[wv] = lm;
    __syncthreads();
    m = fmaxf(fmaxf(r1[0], r1[1]), fmaxf(r1[2], r1[3]));
    float ls = 0.f;
    #pragma unroll
    for (int i = 0; i < 16; ++i) ls += __expf(s[t + 256 * i] - m);
    ls = wsum(ls);
    if (lane == 0) r2[wv] = ls;
    __syncthreads();
    inv = 1.f / (r2[0] + r2[1] + r2[2] + r2[3]);
}

// ---------------------------------------------------------------- K1: MLPs
__global__ __launch_bounds__(256) void k_mlp(
    const float* __restrict__ U, const float* __restrict__ V,
    const float* __restrict__ w_r, const float* __restrict__ b_r,
    const float* __restrict__ Wu0, const float* __restrict__ bu0,
    const float* __restrict__ Wu1, const float* __restrict__ bu1,
    const float* __restrict__ Wv0, const float* __restrict__ bv0,
    const float* __restrict__ Wv1, const float* __restrict__ bv1,
    float* __restrict__ Uh, float* __restrict__ Vh,
    unsigned short* __restrict__ Uhb, unsigned short* __restrict__ Vhb)
{
    int gt = blockIdx.x * 256 + threadIdx.x;
    int wid = gt >> 6;
    int lane = gt & 63;

    float er = b_r[lane];
    #pragma unroll
    for (int s = 0; s < 5; ++s) er += (float)(s + 1) * w_r[s * 64 + lane];

    const int isV = (wid >= 2048);
    const float* X  = isV ? V   : U;
    const float* W0 = isV ? Wv0 : Wu0;
    const float* B0 = isV ? bv0 : bu0;
    const float* W1 = isV ? Wv1 : Wu1;
    const float* B1 = isV ? bv1 : bu1;
    float* Hout          = isV ? Vh  : Uh;
    unsigned short* Hb   = isV ? Vhb : Uhb;
    int r0 = (wid & 2047) * 4;

    float x[4];
    #pragma unroll
    for (int j = 0; j < 4; ++j) x[j] = X[(r0 + j) * 64 + lane];

    float h0c = B0[lane];
    for (int k = 0; k < 64; ++k) h0c += __shfl(er, k) * W0[(64 + k) * 64 + lane];

    float h0[4];
    #pragma unroll
    for (int j = 0; j < 4; ++j) h0[j] = h0c;
    for (int k = 0; k < 64; ++k) {
        float wv = W0[k * 64 + lane];
        #pragma unroll
        for (int j = 0; j < 4; ++j) h0[j] += __shfl(x[j], k) * wv;
    }
    #pragma unroll
    for (int j = 0; j < 4; ++j) h0[j] = fmaxf(h0[j], 0.f);

    float h1[4];
    #pragma unroll
    for (int j = 0; j < 4; ++j) h1[j] = B1[lane];
    for (int k = 0; k < 64; ++k) {
        float wv = W1[k * 64 + lane];
        #pragma unroll
        for (int j = 0; j < 4; ++j) h1[j] += __shfl(h0[j], k) * wv;
    }
    #pragma unroll
    for (int j = 0; j < 4; ++j) {
        h1[j] = fmaxf(h1[j], 0.f);
        Hout[(r0 + j) * 64 + lane] = h1[j];
    }
    // blocked bf16: element (r,d) at (r>>3)*512 + (d>>4)*128 + (d&15)*8 + (r&7)
    unsigned pw[2];
    #pragma unroll
    for (int q = 0; q < 2; ++q) pw[q] = f2bf1(h1[2*q]) | (f2bf1(h1[2*q+1]) << 16);
    unsigned short* dst = Hb + (size_t)(r0 >> 3) * 512 + (lane >> 4) * 128
                        + (lane & 15) * 8 + (r0 & 7);
    *(uint2*)dst = make_uint2(pw[0], pw[1]);
}

// --------------------------------------------------------------- K2: GEMMs
__global__ __launch_bounds__(256) void k_gemm(
    const float* __restrict__ R, const float* __restrict__ S,
    const int* __restrict__ bu,
    const unsigned short* __restrict__ Uhb, const unsigned short* __restrict__ Vhb,
    float* __restrict__ PpI, float* __restrict__ PpS, float* __restrict__ Qp)
{
    __shared__ alignas(16) char QLDS[3][20480];   // 60 KB: 16KB A + 4KB B per buf
    const int bid = blockIdx.x;
    const int t = threadIdx.x;
    const int w = t >> 6, l = t & 63, lg = l >> 4, lr = l & 15;

    if (bid % 3 == 0) {
        // ---------------- Q path: Q = R^T @ Uh
        const int qidx = bid / 3;          // 0..511
        const int iw = qidx & 63;
        const int kz = qidx >> 6;          // 0..7
        const int i0 = iw * QW;
        const int u0 = kz * QSLAB;

        f32x4 acc[2][4] = {};

        // stage step s into QLDS[s%3]: A tile [32u x 128i] f32 (wave w inst q
        // covers rows 2*(4q+w)..+1, 512 B contiguous each) + B slice 4 KB
        // (blocked Uhb rows u0+32s..+32, wave w stages bytes w*1024..+1024).
        #define QSTAGE(s)                                                         \
        {                                                                         \
            char* dstA = QLDS[(s) % 3];                                           \
            _Pragma("unroll")                                                     \
            for (int q = 0; q < 4; ++q) {                                         \
                const int rloc = 2 * (4 * q + w);                                 \
                const float* g = R + ((size_t)(u0 + (s) * 32 + rloc) + (l >> 5)) * 8192 \
                               + i0 + (l & 31) * 4;                               \
                __builtin_amdgcn_global_load_lds(                                 \
                    (const __attribute__((address_space(1))) void*)g,             \
                    (__attribute__((address_space(3))) void*)(dstA + rloc * 512 + l * 16), \
                    16, 0, 0);                                                    \
            }                                                                     \
            const char* bsrc = (const char*)Uhb                                   \
                + ((size_t)((u0 + (s) * 32) >> 3)) * 1024 + w * 1024 + l * 16;    \
            __builtin_amdgcn_global_load_lds(                                     \
                (const __attribute__((address_space(1))) void*)bsrc,              \
                (__attribute__((address_space(3))) void*)(dstA + 16384 + w * 1024 + l * 16), \
                16, 0, 0);                                                        \
        }

        #define QCOMP(s)                                                          \
        {                                                                         \
            const char* buf = QLDS[(s) % 3];                                      \
            const float* La = (const float*)buf;                                  \
            const short* Lbb = (const short*)(buf + 16384);                       \
            bf16x8 bfrag[4];                                                      \
            _Pragma("unroll")                                                     \
            for (int c = 0; c < 4; ++c)                                           \
                bfrag[c] = *(const bf16x8*)(Lbb + lg * 512 + c * 128 + lr * 8);   \
            _Pragma("unroll")                                                     \
            for (int f = 0; f < 2; ++f) {                                         \
                const int iloc = w * 32 + f * 16 + lr;                            \
                float av[8];                                                      \
                _Pragma("unroll")                                                 \
                for (int j = 0; j < 8; ++j) av[j] = La[(8 * lg + j) * QW + iloc]; \
                union { bf16x8 v; unsigned u[4]; } af;                            \
                _Pragma("unroll")                                                 \
                for (int qq = 0; qq < 4; ++qq)                                    \
                    af.u[qq] = f2bf1(av[2*qq]) | (f2bf1(av[2*qq+1]) << 16);       \
                _Pragma("unroll")                                                 \
                for (int c = 0; c < 4; ++c)                                       \
                    acc[f][c] = __builtin_amdgcn_mfma_f32_16x16x32_bf16(af.v, bfrag[c], acc[f][c], 0, 0, 0); \
            }                                                                     \
        }

        QSTAGE(0); QSTAGE(1); QSTAGE(2);     // 15 insts/wave in flight

        for (int s = 0; s < QSTEPS - 2; ++s) {
            // <=10 outstanding => oldest stage (5 insts) landed
            asm volatile("s_waitcnt vmcnt(10)" ::: "memory");
            __builtin_amdgcn_s_barrier();
            QCOMP(s);
            asm volatile("s_waitcnt lgkmcnt(0)" ::: "memory");
            __builtin_amdgcn_sched_barrier(0);
            __builtin_amdgcn_s_barrier();
            if (s + 3 < QSTEPS) QSTAGE(s + 3);
        }
        asm volatile("s_waitcnt vmcnt(5)" ::: "memory");
        __builtin_amdgcn_s_barrier();
        QCOMP(QSTEPS - 2);
        asm volatile("s_waitcnt vmcnt(0)" ::: "memory");
        __builtin_amdgcn_s_barrier();
        QCOMP(QSTEPS - 1);

        #pragma unroll
        for (int f = 0; f < 2; ++f) {
            float* out = Qp + (size_t)(kz * 8192 + i0 + w * 32 + f * 16 + lg * 4) * 64 + lr;
            #pragma unroll
            for (int c = 0; c < 4; ++c) {
                #pragma unroll
                for (int j = 0; j < 4; ++j) out[j * 64 + c * 16] = acc[f][c][j];
            }
        }
        #undef QSTAGE
        #undef QCOMP
    } else {
        // ---------------- P path: rows gathered by bu, depth-4 reg pipeline
        const int pidx = bid - bid / 3 - 1;   // 0..1023
        const int gP = PKZ * 64;              // 512
        const int isS = pidx >= gP;
        int q = isS ? pidx - gP : pidx;
        int tile = q & 63, kz = q >> 6;

        int brow = tile * 64 + w * 16 + lr;
        int ridx = bu[brow];
        const float* A = (isS ? S : R) + (size_t)ridx * 8192 + kz * PKLEN + lg * 8;
        const unsigned short* Bb = (isS ? Uhb : Vhb)
                                 + (size_t)((kz * PKLEN) >> 3) * 512 + lr * 8;

        f32x4 acc[4] = {};
        f32x4 b0[4], b1[4];
        #pragma unroll
        for (int d = 0; d < 4; ++d) {
            b0[d] = ((const f32x4*)(A + d * 32))[0];
            b1[d] = ((const f32x4*)(A + d * 32))[1];
        }

        #pragma unroll 4
        for (int ks = 0; ks < PKITERS - 4; ++ks) {
            const int slot = ks & 3;
            union { bf16x8 v; unsigned u[4]; } af;
            af.u[0] = f2bf1(b0[slot].x) | (f2bf1(b0[slot].y) << 16);
            af.u[1] = f2bf1(b0[slot].z) | (f2bf1(b0[slot].w) << 16);
            af.u[2] = f2bf1(b1[slot].x) | (f2bf1(b1[slot].y) << 16);
            af.u[3] = f2bf1(b1[slot].z) | (f2bf1(b1[slot].w) << 16);
            b0[slot] = ((const f32x4*)(A + (ks + 4) * 32))[0];
            b1[slot] = ((const f32x4*)(A + (ks + 4) * 32))[1];
            const unsigned short* bp = Bb + (size_t)(ks * 4 + lg) * 512;
            #pragma unroll
            for (int c = 0; c < 4; ++c) {
                bf16x8 bf = *(const bf16x8*)(bp + c * 128);
                acc[c] = __builtin_amdgcn_mfma_f32_16x16x32_bf16(af.v, bf, acc[c], 0, 0, 0);
            }
        }
        #pragma unroll
        for (int ks = PKITERS - 4; ks < PKITERS; ++ks) {
            const int slot = ks & 3;
            union { bf16x8 v; unsigned u[4]; } af;
            af.u[0] = f2bf1(b0[slot].x) | (f2bf1(b0[slot].y) << 16);
            af.u[1] = f2bf1(b0[slot].z) | (f2bf1(b0[slot].w) << 16);
            af.u[2] = f2bf1(b1[slot].x) | (f2bf1(b1[slot].y) << 16);
            af.u[3] = f2bf1(b1[slot].z) | (f2bf1(b1[slot].w) << 16);
            const unsigned short* bp = Bb + (size_t)(ks * 4 + lg) * 512;
            #pragma unroll
            for (int c = 0; c < 4; ++c) {
                bf16x8 bf = *(const bf16x8*)(bp + c * 128);
                acc[c] = __builtin_amdgcn_mfma_f32_16x16x32_bf16(af.v, bf, acc[c], 0, 0, 0);
            }
        }

        float* out = (isS ? PpS : PpI)
                   + (size_t)(kz * 4096 + tile * 64 + w * 16 + lg * 4) * 64 + lr;
        #pragma unroll
        for (int c = 0; c < 4; ++c) {
            #pragma unroll
            for (int j = 0; j < 4; ++j) out[j * 64 + c * 16] = acc[c][j];
        }
    }
}

// ------------------------------------------------------- S1: scores A and M
__global__ __launch_bounds__(256) void k_scoreAM(
    const int* __restrict__ bu, const int* __restrict__ bi,
    const float* __restrict__ Uh, const float* __restrict__ Vh,
    const float* __restrict__ W1A, const float* __restrict__ b1A,
    const float* __restrict__ w2A, const float* __restrict__ b2A,
    const float* __restrict__ W1M, const float* __restrict__ b1M,
    const float* __restrict__ w2M, const float* __restrict__ b2M,
    float* __restrict__ sA, float* __restrict__ sM)
{
    int gt = blockIdx.x * 256 + threadIdx.x;
    int wid = gt >> 6, lane = gt & 63;
    int b0 = wid * 2;
    float ub[2], vb[2];
    #pragma unroll
    for (int j = 0; j < 2; ++j) {
        ub[j] = Uh[(size_t)bu[b0 + j] * 64 + lane];
        vb[j] = Vh[(size_t)bi[b0 + j] * 64 + lane];
    }
    float hA[2], hM[2];
    #pragma unroll
    for (int j = 0; j < 2; ++j) { hA[j] = b1A[lane]; hM[j] = b1M[lane]; }
    for (int k = 0; k < 64; ++k) {
        float wa0 = W1A[k * 64 + lane], wa1 = W1A[(64 + k) * 64 + lane];
        float wm0 = W1M[k * 64 + lane], wm1 = W1M[(64 + k) * 64 + lane];
        #pragma unroll
        for (int j = 0; j < 2; ++j) {
            float sv = __shfl(vb[j], k), su = __shfl(ub[j], k);
            hA[j] += sv * wa0 + su * wa1;   // cat(Vb, Ub)
            hM[j] += su * wm0 + sv * wm1;   // cat(Ub, Vb)
        }
    }
    float w2a = w2A[lane], w2m = w2M[lane];
    #pragma unroll
    for (int j = 0; j < 2; ++j) {
        float sa = wsum(fmaxf(hA[j], 0.f) * w2a);
        float sm = wsum(fmaxf(hM[j], 0.f) * w2m);
        if (lane == 0) { sA[b0 + j] = sa + b2A[0]; sM[b0 + j] = sm + b2M[0]; }
    }
}

// ------------------------------------------------- S2: H_I and B-scores
__global__ __launch_bounds__(256) void k_HI_scoreB(
    const float* __restrict__ PpI, const float* __restrict__ sA,
    const int* __restrict__ bu, const float* __restrict__ Uh,
    const float* __restrict__ W_I, const float* __restrict__ b_I,
    const float* __restrict__ W1B, const float* __restrict__ b1B,
    const float* __restrict__ w2B, const float* __restrict__ b2B,
    float* __restrict__ HI, float* __restrict__ sB)
{
    float m, inv;
    block_softmax_stats(sA, m, inv);
    int wid = blockIdx.x * 4 + (threadIdx.x >> 6);
    int lane = threadIdx.x & 63;
    int b0 = wid * 2;
    float p[2];
    #pragma unroll
    for (int j = 0; j < 2; ++j) {
        int b = b0 + j;
        float a = 0.f;
        #pragma unroll
        for (int kz = 0; kz < PKZ; ++kz)
            a += PpI[(size_t)(kz * 4096 + b) * 64 + lane];
        p[j] = a * (__expf(sA[b] - m) * inv);
    }
    float h[2];
    #pragma unroll
    for (int j = 0; j < 2; ++j) h[j] = b_I[lane];
    for (int k = 0; k < 64; ++k) {
        float wv = W_I[k * 64 + lane];
        #pragma unroll
        for (int j = 0; j < 2; ++j) h[j] += __shfl(p[j], k) * wv;
    }
    float ub[2];
    #pragma unroll
    for (int j = 0; j < 2; ++j) {
        h[j] = fmaxf(h[j], 0.f);
        HI[(size_t)(b0 + j) * 64 + lane] = h[j];
        ub[j] = Uh[(size_t)bu[b0 + j] * 64 + lane];
    }
    float h2[2];
    #pragma unroll
    for (int j = 0; j < 2; ++j) h2[j] = b1B[lane];
    for (int k = 0; k < 64; ++k) {
        float w0 = W1B[k * 64 + lane], w1 = W1B[(64 + k) * 64 + lane];
        #pragma unroll
        for (int j = 0; j < 2; ++j) h2[j] += __shfl(h[j], k) * w0 + __shfl(ub[j], k) * w1;
    }
    float w2 = w2B[lane];
    #pragma unroll
    for (int j = 0; j < 2; ++j) {
        float sv = wsum(fmaxf(h2[j], 0.f) * w2);
        if (lane == 0) sB[b0 + j] = sv + b2B[0];
    }
}

// ------------------------------------------------- S3: H_S then H
__global__ __launch_bounds__(256) void k_HS_H(
    const float* __restrict__ PpS, const float* __restrict__ sB,
    const float* __restrict__ HI,
    const float* __restrict__ W_Sm, const float* __restrict__ b_Sm,
    const float* __restrict__ Wc0, const float* __restrict__ bc0,
    const float* __restrict__ Wc1, const float* __restrict__ bc1,
    float* __restrict__ Hout)
{
    float m, inv;
    block_softmax_stats(sB, m, inv);
    int wid = blockIdx.x * 4 + (threadIdx.x >> 6);
    int lane = threadIdx.x & 63;
    int b0 = wid * 2;
    float p[2];
    #pragma unroll
    for (int j = 0; j < 2; ++j) {
        int b = b0 + j;
        float a = 0.f;
        #pragma unroll
        for (int kz = 0; kz < PKZ; ++kz)
            a += PpS[(size_t)(kz * 4096 + b) * 64 + lane];
        p[j] = a * (__expf(sB[b] - m) * inv);
    }
    float hs[2];
    #pragma unroll
    for (int j = 0; j < 2; ++j) hs[j] = b_Sm[lane];
    for (int k = 0; k < 64; ++k) {
        float wv = W_Sm[k * 64 + lane];
        #pragma unroll
        for (int j = 0; j < 2; ++j) hs[j] += __shfl(p[j], k) * wv;
    }
    float hi[2];
    #pragma unroll
    for (int j = 0; j < 2; ++j) {
        hs[j] = fmaxf(hs[j], 0.f);
        hi[j] = HI[(size_t)(b0 + j) * 64 + lane];
    }
    float h0[2];
    #pragma unroll
    for (int j = 0; j < 2; ++j) h0[j] = bc0[lane];
    for (int k = 0; k < 64; ++k) {
        float w0 = Wc0[k * 64 + lane], w1 = Wc0[(64 + k) * 64 + lane];
        #pragma unroll
        for (int j = 0; j < 2; ++j) h0[j] += __shfl(hi[j], k) * w0 + __shfl(hs[j], k) * w1;
    }
    #pragma unroll
    for (int j = 0; j < 2; ++j) h0[j] = fmaxf(h0[j], 0.f);
    float h1[2];
    #pragma unroll
    for (int j = 0; j < 2; ++j) h1[j] = bc1[lane];
    for (int k = 0; k < 64; ++k) {
        float wv = Wc1[k * 64 + lane];
        #pragma unroll
        for (int j = 0; j < 2; ++j) h1[j] += __shfl(h0[j], k) * wv;
    }
    #pragma unroll
    for (int j = 0; j < 2; ++j) Hout[(size_t)(b0 + j) * 64 + lane] = fmaxf(h1[j], 0.f);
}

// ------------------------------------------------- S4: Z then G (output)
__global__ __launch_bounds__(256) void k_Z_G(
    const float* __restrict__ Qp, const float* __restrict__ sM,
    const int* __restrict__ bi, const float* __restrict__ H,
    const float* __restrict__ W_Z, const float* __restrict__ b_Z,
    const float* __restrict__ Wg0, const float* __restrict__ bg0,
    const float* __restrict__ Wg1, const float* __restrict__ bg1,
    float* __restrict__ G)
{
    float m, inv;
    block_softmax_stats(sM, m, inv);
    int wid = blockIdx.x * 4 + (threadIdx.x >> 6);
    int lane = threadIdx.x & 63;
    int b0 = wid * 2;
    float p[2];
    #pragma unroll
    for (int j = 0; j < 2; ++j) {
        int b = b0 + j;
        int it = bi[b];
        float a = 0.f;
        #pragma unroll
        for (int kz = 0; kz < QKZ; ++kz)
            a += Qp[(size_t)(kz * 8192 + it) * 64 + lane];
        p[j] = a * (__expf(sM[b] - m) * inv);
    }
    float z[2];
    #pragma unroll
    for (int j = 0; j < 2; ++j) z[j] = b_Z[lane];
    for (int k = 0; k < 64; ++k) {
        float wv = W_Z[k * 64 + lane];
        #pragma unroll
        for (int j = 0; j < 2; ++j) z[j] += __shfl(p[j], k) * wv;
    }
    float hr[2];
    #pragma unroll
    for (int j = 0; j < 2; ++j) {
        z[j] = fmaxf(z[j], 0.f);
        hr[j] = H[(size_t)(b0 + j) * 64 + lane];
    }
    float g0[2];
    #pragma unroll
    for (int j = 0; j < 2; ++j) g0[j] = bg0[lane];
    for (int k = 0; k < 64; ++k) {
        float w0 = Wg0[k * 64 + lane], w1 = Wg0[(64 + k) * 64 + lane];
        #pragma unroll
        for (int j = 0; j < 2; ++j) g0[j] += __shfl(hr[j], k) * w0 + __shfl(z[j], k) * w1;
    }
    #pragma unroll
    for (int j = 0; j < 2; ++j) g0[j] = fmaxf(g0[j], 0.f);
    float g1[2];
    #pragma unroll
    for (int j = 0; j < 2; ++j) g1[j] = bg1[lane];
    for (int k = 0; k < 64; ++k) {
        float wv = Wg1[k * 64 + lane];
        #pragma unroll
        for (int j = 0; j < 2; ++j) g1[j] += __shfl(g0[j], k) * wv;
    }
    #pragma unroll
    for (int j = 0; j < 2; ++j) G[(size_t)(b0 + j) * 64 + lane] = fmaxf(g1[j], 0.f);
}

// ---------------------------------------------------------------------------
extern "C" void kernel_launch(void* const* d_in, const int* in_sizes, int n_in,
                              void* d_out, int out_size, void* d_ws, size_t ws_size,
                              hipStream_t stream)
{
    (void)in_sizes; (void)n_in; (void)out_size; (void)ws_size;
    const int*   bu  = (const int*)  d_in[0];
    const int*   bi  = (const int*)  d_in[1];
    const float* R   = (const float*)d_in[2];
    const float* S   = (const float*)d_in[3];
    const float* U   = (const float*)d_in[4];
    const float* V   = (const float*)d_in[5];
    const float* w_r = (const float*)d_in[6];
    const float* b_r = (const float*)d_in[7];
    const float* Wu0 = (const float*)d_in[8];
    const float* bu0 = (const float*)d_in[9];
    const float* Wu1 = (const float*)d_in[10];
    const float* bu1 = (const float*)d_in[11];
    const float* Wv0 = (const float*)d_in[12];
    const float* bv0 = (const float*)d_in[13];
    const float* Wv1 = (const float*)d_in[14];
    const float* bv1 = (const float*)d_in[15];
    const float* Wc0 = (const float*)d_in[16];
    const float* bc0 = (const float*)d_in[17];
    const float* Wc1 = (const float*)d_in[18];
    const float* bc1 = (const float*)d_in[19];
    const float* Wg0 = (const float*)d_in[20];
    const float* bg0 = (const float*)d_in[21];
    const float* Wg1 = (const float*)d_in[22];
    const float* bg1 = (const float*)d_in[23];
    const float* W_I = (const float*)d_in[24];
    const float* b_I = (const float*)d_in[25];
    const float* W_Sm= (const float*)d_in[26];
    const float* b_Sm= (const float*)d_in[27];
    const float* W1A = (const float*)d_in[28];
    const float* b1A = (const float*)d_in[29];
    const float* w2A = (const float*)d_in[30];
    const float* b2A = (const float*)d_in[31];
    const float* W1B = (const float*)d_in[32];
    const float* b1B = (const float*)d_in[33];
    const float* w2B = (const float*)d_in[34];
    const float* b2B = (const float*)d_in[35];
    const float* W1M = (const float*)d_in[36];
    const float* b1M = (const float*)d_in[37];
    const float* w2M = (const float*)d_in[38];
    const float* b2M = (const float*)d_in[39];
    const float* W_Z = (const float*)d_in[40];
    const float* b_Z = (const float*)d_in[41];

    char* ws = (char*)d_ws;
    size_t off = 0;
    float*          Uh  = (float*)(ws + off);          off += 2ull << 20;
    float*          Vh  = (float*)(ws + off);          off += 2ull << 20;
    unsigned short* Uhb = (unsigned short*)(ws + off); off += 1ull << 20;
    unsigned short* Vhb = (unsigned short*)(ws + off); off += 1ull << 20;
    float*          PpI = (float*)(ws + off);          off += (size_t)PKZ << 20;
    float*          PpS = (float*)(ws + off);          off += (size_t)PKZ << 20;
    float*          Qp  = (float*)(ws + off);          off += (size_t)(2 * QKZ) << 20;
    float*          sA  = (float*)(ws + off);
    float*          sM  = sA + 4096;
    float*          sB  = sA + 8192;                   off += 3 * 4096 * 4 + 4096;
    float*          HI  = (float*)(ws + off);          off += 1ull << 20;
    float*          Hh  = (float*)(ws + off);

    k_mlp<<<1024, 256, 0, stream>>>(U, V, w_r, b_r, Wu0, bu0, Wu1, bu1,
                                    Wv0, bv0, Wv1, bv1, Uh, Vh, Uhb, Vhb);
    k_gemm<<<QBLOCKS + PBLOCKS, 256, 0, stream>>>(R, S, bu, Uhb, Vhb,
                                                  PpI, PpS, Qp);
    k_scoreAM<<<512, 256, 0, stream>>>(bu, bi, Uh, Vh, W1A, b1A, w2A, b2A,
                                       W1M, b1M, w2M, b2M, sA, sM);
    k_HI_scoreB<<<512, 256, 0, stream>>>(PpI, sA, bu, Uh, W_I, b_I,
                                         W1B, b1B, w2B, b2B, HI, sB);
    k_HS_H<<<512, 256, 0, stream>>>(PpS, sB, HI, W_Sm, b_Sm, Wc0, bc0, Wc1, bc1,
                                    Hh);
    k_Z_G<<<512, 256, 0, stream>>>(Qp, sM, bi, Hh, W_Z, b_Z, Wg0, bg0, Wg1, bg1,
                                   (float*)d_out);
}